// Round 3
// baseline (6055.007 us; speedup 1.0000x reference)
//
#include <hip/hip_runtime.h>

typedef __bf16 bf16;
typedef __bf16 bf16x8 __attribute__((ext_vector_type(8)));
typedef float  f32x4  __attribute__((ext_vector_type(4)));

#define T_STEPS 128
#define BATCH   256
#define HD      1024
#define N4H     4096
#define EMB_D   128

__device__ __forceinline__ float fast_sigmoid(float x) {
    return 1.0f / (1.0f + __expf(-x));
}
__device__ __forceinline__ float fast_tanh(float x) {
    return 1.0f - 2.0f / (__expf(2.0f * x) + 1.0f);
}

// ---------------- prep: P[v][n] = (emb[v] @ Wx_gate)[hcol] + b_gate[hcol],
// n = 4*hcol + gate, gate order (g,i,f,o) ----------------
__global__ void build_P(const float* __restrict__ emb,
                        const float* __restrict__ Wgx, const float* __restrict__ Wix,
                        const float* __restrict__ Wfx, const float* __restrict__ Wox,
                        const float* __restrict__ bg,  const float* __restrict__ bi,
                        const float* __restrict__ bfv, const float* __restrict__ bo,
                        float* __restrict__ P)
{
    int n = blockIdx.x * 256 + threadIdx.x;
    int v  = n >> 12;
    int nn = n & (N4H - 1);
    int hcol = nn >> 2, gate = nn & 3;
    const float* Wx = (gate == 0) ? Wgx : (gate == 1) ? Wix : (gate == 2) ? Wfx : Wox;
    const float* bb = (gate == 0) ? bg  : (gate == 1) ? bi  : (gate == 2) ? bfv : bo;
    float s = bb[hcol];
    for (int e = 0; e < EMB_D; ++e)
        s += emb[v * EMB_D + e] * Wx[e * HD + hcol];
    P[n] = s;
}

// ---------------- prep: WhpT[n][k] = Wh_gate[k][hcol] as bf16 ----------------
__global__ void build_W(const float* __restrict__ Wgh, const float* __restrict__ Wih,
                        const float* __restrict__ Wfh, const float* __restrict__ Woh,
                        bf16* __restrict__ WhpT)
{
    __shared__ float tile[64][65];
    int bid  = blockIdx.x;
    int gate = bid >> 8;
    int t2   = bid & 255;
    int kt = t2 >> 4, ht = t2 & 15;
    const float* W = (gate == 0) ? Wgh : (gate == 1) ? Wih : (gate == 2) ? Wfh : Woh;
    int tid = threadIdx.x;
    #pragma unroll
    for (int it = 0; it < 16; ++it) {
        int idx = it * 256 + tid;
        int kk = idx >> 6, hh = idx & 63;
        tile[kk][hh] = W[(size_t)(kt * 64 + kk) * HD + ht * 64 + hh];
    }
    __syncthreads();
    #pragma unroll
    for (int it = 0; it < 16; ++it) {
        int idx = it * 256 + tid;
        int hh = idx >> 6, kk = idx & 63;
        int n = (ht * 64 + hh) * 4 + gate;
        WhpT[(size_t)n * HD + kt * 64 + kk] = (bf16)tile[kk][hh];
    }
}

// ---------------- main persistent kernel ----------------
// 256 blocks x 256 threads, 1/CU. mi=(bid>>1)&3 (XCD-paired groups of 64
// blocks), ni in 0..63. Block tile: m=64 (batch), n=64 (gate-cols). Waves
// split 2m x 2n. No __syncthreads in the step loop: waves arrive/spin
// independently on a per-group monotonic counter (release-sequence barrier).
// x/P for step t+1 are prefetched into regs between arrive and wait.
__global__ __launch_bounds__(256, 1)
void lstm_main(const int* __restrict__ x, const float* __restrict__ P,
               const bf16* __restrict__ WhpT, bf16* __restrict__ hbuf,
               int* __restrict__ bar)
{
    __shared__ bf16 Alds[64][1032];   // block's A slice (n=64 rows x K=1024), +8 pad

    const int tid  = threadIdx.x;
    const int lane = tid & 63;
    const int wid  = tid >> 6;
    const int wm = wid & 1, wn = wid >> 1;   // 2m x 2n wave grid
    const int frow = lane & 15;
    const int kgrp = lane >> 4;
    const int bid = blockIdx.x;
    const int mi = (bid >> 1) & 3;                  // group -> XCD pair (heuristic)
    const int ni = ((bid >> 3) << 1) | (bid & 1);   // 0..63

    // persistent A load (once)
    #pragma unroll
    for (int it = 0; it < 32; ++it) {
        int idx = it * 256 + tid;
        int row = idx >> 7, g = idx & 127;
        *(bf16x8*)&Alds[row][g * 8] =
            *(const bf16x8*)(WhpT + (size_t)(ni * 64 + row) * HD + g * 8);
    }
    __syncthreads();

    int* ctr = bar + mi * 64;    // one line per group, monotonic arrivals

    const int mg0 = mi * 64 + wm * 32 + frow;        // fm=0 batch row
    const int mg1 = mg0 + 16;                        // fm=1 batch row
    const int nb0 = (ni * 16 + wn * 8 + kgrp) * 4;   // fn=0 P offset
    const int nb1 = nb0 + 16;                        // fn=1 (+4 hcols)*4
    const int hc0 = ni * 16 + wn * 8 + kgrp;         // fn=0 h col
    const int hc1 = hc0 + 4;

    float st[2][2] = {{0.f, 0.f}, {0.f, 0.f}};
    f32x4 acc[2][2];

    // prefetch step-0 accumulator init (h(0)=0 -> pre = P only at t=0)
    {
        int xv0 = x[mg0], xv1 = x[mg1];
        acc[0][0] = *(const f32x4*)(P + (size_t)xv0 * N4H + nb0);
        acc[0][1] = *(const f32x4*)(P + (size_t)xv1 * N4H + nb0);
        acc[1][0] = *(const f32x4*)(P + (size_t)xv0 * N4H + nb1);
        acc[1][1] = *(const f32x4*)(P + (size_t)xv1 * N4H + nb1);
    }

    for (int t = 0; t < T_STEPS; ++t) {
        const bf16* hin  = hbuf + (size_t)(t & 1) * BATCH * HD;
        bf16*       hout = hbuf + (size_t)((t + 1) & 1) * BATCH * HD;

        if (t > 0) {
            const bf16* Br0 = hin + (size_t)mg0 * HD + kgrp * 8;
            const bf16* Br1 = hin + (size_t)mg1 * HD + kgrp * 8;
            bf16x8 rb[2][8];
            #pragma unroll
            for (int ks = 0; ks < 4; ++ks) {
                rb[0][ks * 2]     = *(const bf16x8*)(Br0 + ks * 32);
                rb[0][ks * 2 + 1] = *(const bf16x8*)(Br1 + ks * 32);
            }
            #pragma unroll
            for (int kc = 0; kc < 8; ++kc) {
                const int cur = kc & 1, nxt = cur ^ 1;
                if (kc < 7) {
                    #pragma unroll
                    for (int ks = 0; ks < 4; ++ks) {
                        rb[nxt][ks * 2]     = *(const bf16x8*)(Br0 + (kc + 1) * 128 + ks * 32);
                        rb[nxt][ks * 2 + 1] = *(const bf16x8*)(Br1 + (kc + 1) * 128 + ks * 32);
                    }
                }
                #pragma unroll
                for (int ks = 0; ks < 4; ++ks) {
                    bf16x8 af0 = *(const bf16x8*)&Alds[wn * 32 + frow]
                                                      [kc * 128 + ks * 32 + kgrp * 8];
                    bf16x8 af1 = *(const bf16x8*)&Alds[wn * 32 + 16 + frow]
                                                      [kc * 128 + ks * 32 + kgrp * 8];
                    acc[0][0] = __builtin_amdgcn_mfma_f32_16x16x32_bf16(af0, rb[cur][ks * 2],     acc[0][0], 0, 0, 0);
                    acc[0][1] = __builtin_amdgcn_mfma_f32_16x16x32_bf16(af0, rb[cur][ks * 2 + 1], acc[0][1], 0, 0, 0);
                    acc[1][0] = __builtin_amdgcn_mfma_f32_16x16x32_bf16(af1, rb[cur][ks * 2],     acc[1][0], 0, 0, 0);
                    acc[1][1] = __builtin_amdgcn_mfma_f32_16x16x32_bf16(af1, rb[cur][ks * 2 + 1], acc[1][1], 0, 0, 0);
                }
            }
        }

        // gates + state update (lane-local), direct h store (8B segments)
        #pragma unroll
        for (int fn = 0; fn < 2; ++fn) {
            int hc = fn ? hc1 : hc0;
            #pragma unroll
            for (int fm = 0; fm < 2; ++fm) {
                int mg = fm ? mg1 : mg0;
                f32x4 pre = acc[fn][fm];
                float gg = fast_tanh(pre[0]);
                float ii = fast_sigmoid(pre[1]);
                float ff = fast_sigmoid(pre[2]);
                float oo = fast_sigmoid(pre[3]);
                float s = gg * ii + st[fn][fm] * ff;
                st[fn][fm] = s;
                hout[(size_t)mg * HD + hc] = (bf16)(fast_tanh(s) * oo);
            }
        }

        if (t < T_STEPS - 1) {
            // release-arrive: orders this wave's h stores before the increment
            if (lane == 0)
                __hip_atomic_fetch_add(ctr, 1, __ATOMIC_RELEASE, __HIP_MEMORY_SCOPE_AGENT);
            // prefetch next step's x/P (constant data) into regs during the wait
            {
                int xv0 = x[(t + 1) * BATCH + mg0], xv1 = x[(t + 1) * BATCH + mg1];
                acc[0][0] = *(const f32x4*)(P + (size_t)xv0 * N4H + nb0);
                acc[0][1] = *(const f32x4*)(P + (size_t)xv1 * N4H + nb0);
                acc[1][0] = *(const f32x4*)(P + (size_t)xv0 * N4H + nb1);
                acc[1][1] = *(const f32x4*)(P + (size_t)xv1 * N4H + nb1);
            }
            const int tgt = 256 * (t + 1);   // 64 blocks x 4 waves per group
            while (__hip_atomic_load(ctr, __ATOMIC_RELAXED, __HIP_MEMORY_SCOPE_AGENT) < tgt)
                __builtin_amdgcn_s_sleep(1);
            (void)__hip_atomic_load(ctr, __ATOMIC_ACQUIRE, __HIP_MEMORY_SCOPE_AGENT);
        }
    }
}

// ---------------- final projection: out[b][c] = h_T[b] @ Wph + bp ----------------
__global__ void proj_out(const bf16* __restrict__ h, const float* __restrict__ Wph,
                         const float* __restrict__ bp, float* __restrict__ out)
{
    __shared__ float red[256][10];
    int b = blockIdx.x, tid = threadIdx.x;
    float acc[10];
    #pragma unroll
    for (int c = 0; c < 10; ++c) acc[c] = 0.f;
    for (int k = tid; k < HD; k += 256) {
        float hv = (float)h[(size_t)b * HD + k];
        #pragma unroll
        for (int c = 0; c < 10; ++c)
            acc[c] += hv * Wph[k * 10 + c];
    }
    #pragma unroll
    for (int c = 0; c < 10; ++c) red[tid][c] = acc[c];
    __syncthreads();
    for (int s = 128; s > 0; s >>= 1) {
        if (tid < s) {
            #pragma unroll
            for (int c = 0; c < 10; ++c) red[tid][c] += red[tid + s][c];
        }
        __syncthreads();
    }
    if (tid < 10) out[b * 10 + tid] = red[0][tid] + bp[tid];
}

extern "C" void kernel_launch(void* const* d_in, const int* in_sizes, int n_in,
                              void* d_out, int out_size, void* d_ws, size_t ws_size,
                              hipStream_t stream)
{
    const int*   x   = (const int*)  d_in[0];
    const float* emb = (const float*)d_in[1];
    const float* Wgx = (const float*)d_in[2];
    const float* Wgh = (const float*)d_in[3];
    const float* Wix = (const float*)d_in[4];
    const float* Wih = (const float*)d_in[5];
    const float* Wfx = (const float*)d_in[6];
    const float* Wfh = (const float*)d_in[7];
    const float* Wox = (const float*)d_in[8];
    const float* Woh = (const float*)d_in[9];
    const float* bg  = (const float*)d_in[10];
    const float* bi  = (const float*)d_in[11];
    const float* bfv = (const float*)d_in[12];
    const float* bo  = (const float*)d_in[13];
    const float* Wph = (const float*)d_in[14];
    const float* bp  = (const float*)d_in[15];

    char* ws = (char*)d_ws;
    bf16*  WhpT = (bf16*)ws;                                   // 8 MB
    float* P    = (float*)(ws + 8388608);                      // 160 KB
    bf16*  hbuf = (bf16*)(ws + 8388608 + 163840);              // 2 x 512 KB
    int*   bar  = (int*)(ws + 8388608 + 163840 + 1048576);     // 4 groups

    hipMemsetAsync(bar, 0, 4 * 64 * sizeof(int), stream);
    build_P<<<160, 256, 0, stream>>>(emb, Wgx, Wix, Wfx, Wox, bg, bi, bfv, bo, P);
    build_W<<<1024, 256, 0, stream>>>(Wgh, Wih, Wfh, Woh, WhpT);

    void* args[] = { (void*)&x, (void*)&P, (void*)&WhpT, (void*)&hbuf, (void*)&bar };
    hipLaunchCooperativeKernel((void*)lstm_main, dim3(256), dim3(256), args, 0, stream);

    proj_out<<<256, 256, 0, stream>>>(hbuf, Wph, bp, (float*)d_out);
}

// Round 4
// 610.816 us; speedup vs baseline: 9.9130x; 9.9130x over previous
//
#include <hip/hip_runtime.h>

typedef __bf16 bf16;
typedef __bf16 bf16x8 __attribute__((ext_vector_type(8)));
typedef float  f32x4  __attribute__((ext_vector_type(4)));

#define T_STEPS 128
#define BATCH   256
#define HD      1024
#define N4H     4096
#define EMB_D   128

__device__ __forceinline__ float fast_sigmoid(float x) {
    return 1.0f / (1.0f + __expf(-x));
}
__device__ __forceinline__ float fast_tanh(float x) {
    return 1.0f - 2.0f / (__expf(2.0f * x) + 1.0f);
}

// ---------------- prep: P[v][n] = (emb[v] @ Wx_gate)[hcol] + b_gate[hcol],
// n = 4*hcol + gate, gate order (g,i,f,o) ----------------
__global__ void build_P(const float* __restrict__ emb,
                        const float* __restrict__ Wgx, const float* __restrict__ Wix,
                        const float* __restrict__ Wfx, const float* __restrict__ Wox,
                        const float* __restrict__ bg,  const float* __restrict__ bi,
                        const float* __restrict__ bfv, const float* __restrict__ bo,
                        float* __restrict__ P)
{
    int n = blockIdx.x * 256 + threadIdx.x;
    int v  = n >> 12;
    int nn = n & (N4H - 1);
    int hcol = nn >> 2, gate = nn & 3;
    const float* Wx = (gate == 0) ? Wgx : (gate == 1) ? Wix : (gate == 2) ? Wfx : Wox;
    const float* bb = (gate == 0) ? bg  : (gate == 1) ? bi  : (gate == 2) ? bfv : bo;
    float s = bb[hcol];
    for (int e = 0; e < EMB_D; ++e)
        s += emb[v * EMB_D + e] * Wx[e * HD + hcol];
    P[n] = s;
}

// ---------------- prep: WhpT[n][k] = Wh_gate[k][hcol] as bf16 ----------------
__global__ void build_W(const float* __restrict__ Wgh, const float* __restrict__ Wih,
                        const float* __restrict__ Wfh, const float* __restrict__ Woh,
                        bf16* __restrict__ WhpT)
{
    __shared__ float tile[64][65];
    int bid  = blockIdx.x;
    int gate = bid >> 8;
    int t2   = bid & 255;
    int kt = t2 >> 4, ht = t2 & 15;
    const float* W = (gate == 0) ? Wgh : (gate == 1) ? Wih : (gate == 2) ? Wfh : Woh;
    int tid = threadIdx.x;
    #pragma unroll
    for (int it = 0; it < 16; ++it) {
        int idx = it * 256 + tid;
        int kk = idx >> 6, hh = idx & 63;
        tile[kk][hh] = W[(size_t)(kt * 64 + kk) * HD + ht * 64 + hh];
    }
    __syncthreads();
    #pragma unroll
    for (int it = 0; it < 16; ++it) {
        int idx = it * 256 + tid;
        int hh = idx >> 6, kk = idx & 63;
        int n = (ht * 64 + hh) * 4 + gate;
        WhpT[(size_t)n * HD + kt * 64 + kk] = (bf16)tile[kk][hh];
    }
}

// ---------------- main persistent kernel ----------------
// 256 blocks x 512 threads (8 waves), 1 block/CU. Group g = bid>>5 owns batch
// rows [g*32,+32); member j = bid&31 owns gate-cols [j*128,+128). Weights live
// in VGPRs (wave = 32 cols x 512 k, k-split across wave pairs, LDS-reduced).
// h tile staged to XOR-swizzled LDS via device-coherent (sc0 sc1) loads; h
// stores are sc0 sc1 write-through -> no cache invalidates anywhere. One
// relaxed atomic arrive per block per step; only tid 0 spins.
__global__ __launch_bounds__(512, 2)
void lstm_main(const int* __restrict__ x, const float* __restrict__ P,
               const bf16* __restrict__ WhpT, bf16* __restrict__ hbuf,
               int* __restrict__ ctl)
{
    __shared__ bf16  Blds[32][1024];     // 64 KB swizzled h tile
    __shared__ float red[4][64][20];     // 20 KB k-half partials (pad 20 -> conflict-free)

    const int tid  = threadIdx.x;
    const int lane = tid & 63;
    const int wid  = tid >> 6;           // 0..7
    const int w    = wid & 3;            // n-group (32 gate-cols)
    const int kh   = wid >> 2;           // k-half (512 k)
    const int frow = lane & 15;
    const int kgrp = lane >> 4;
    const int bid  = blockIdx.x;
    const int g    = bid >> 5;           // batch group 0..7
    const int j    = bid & 31;           // col member 0..31

    int* bar = ctl + g * 16;

    // ---- persistent A in registers: 32 gate-cols x 512 k per wave ----
    const bf16* Abase = WhpT + (size_t)(j * 128 + w * 32 + frow) * HD + kh * 512 + kgrp * 8;
    bf16x8 Ar[2][16];
    #pragma unroll
    for (int fn = 0; fn < 2; ++fn)
        #pragma unroll
        for (int ks = 0; ks < 16; ++ks)
            Ar[fn][ks] = *(const bf16x8*)(Abase + fn * 16 * HD + ks * 32);

    const int pn0  = j * 128 + w * 32 + kgrp * 4;   // P gate-col base (fn=0)
    const int hc0  = j * 32 + w * 8 + kgrp;         // h col (fn=0)
    const int mr0  = g * 32 + frow;                 // batch row (fm=0)
    const int xorf = frow & 7;
    char* BB = (char*)&Blds[0][0];

    float st[2][2] = {{0.f, 0.f}, {0.f, 0.f}};

    for (int t = 0; t < T_STEPS; ++t) {
        f32x4 acc[2][2];
        if (kh == 0) {
            int xv0 = x[t * BATCH + mr0];
            int xv1 = x[t * BATCH + mr0 + 16];
            acc[0][0] = *(const f32x4*)(P + (size_t)xv0 * N4H + pn0);
            acc[0][1] = *(const f32x4*)(P + (size_t)xv1 * N4H + pn0);
            acc[1][0] = *(const f32x4*)(P + (size_t)xv0 * N4H + pn0 + 16);
            acc[1][1] = *(const f32x4*)(P + (size_t)xv1 * N4H + pn0 + 16);
        } else {
            f32x4 z = {0.f, 0.f, 0.f, 0.f};
            acc[0][0] = z; acc[0][1] = z; acc[1][0] = z; acc[1][1] = z;
        }

        if (t > 0) {
            if (tid == 0) {
                const int tgt = 32 * t;
                long guard = 0;
                while (__hip_atomic_load(bar, __ATOMIC_RELAXED, __HIP_MEMORY_SCOPE_AGENT) < tgt
                       && ++guard < (1L << 24)) {}
            }
            __syncthreads();
            // ---- stage 64 KB h tile into swizzled LDS (device-coherent loads) ----
            const char* src = (const char*)(hbuf + (size_t)(t & 1) * BATCH * HD
                                                 + (size_t)g * 32 * HD);
            f32x4 stg[8];
            #pragma unroll
            for (int i2 = 0; i2 < 8; ++i2)
                asm volatile("global_load_dwordx4 %0, %1, off sc0 sc1"
                             : "=v"(stg[i2]) : "v"(src + (i2 * 512 + tid) * 16));
            asm volatile("s_waitcnt vmcnt(0)" ::: "memory");
            #pragma unroll
            for (int i2 = 0; i2 < 8; ++i2) {
                int c = i2 * 512 + tid;
                int row = c >> 7, cg = c & 127;
                *(f32x4*)(BB + row * 2048 + ((cg ^ (row & 7)) << 4)) = stg[i2];
            }
            __syncthreads();
            // ---- GEMM: acc += A(regs) * B(lds); each wave does its k-half ----
            #pragma unroll
            for (int ks = 0; ks < 16; ++ks) {
                int off = ((kh * 64 + ks * 4 + kgrp) ^ xorf) << 4;
                bf16x8 b0 = *(const bf16x8*)(BB + frow * 2048 + off);
                bf16x8 b1 = *(const bf16x8*)(BB + (frow + 16) * 2048 + off);
                acc[0][0] = __builtin_amdgcn_mfma_f32_16x16x32_bf16(Ar[0][ks], b0, acc[0][0], 0, 0, 0);
                acc[0][1] = __builtin_amdgcn_mfma_f32_16x16x32_bf16(Ar[0][ks], b1, acc[0][1], 0, 0, 0);
                acc[1][0] = __builtin_amdgcn_mfma_f32_16x16x32_bf16(Ar[1][ks], b0, acc[1][0], 0, 0, 0);
                acc[1][1] = __builtin_amdgcn_mfma_f32_16x16x32_bf16(Ar[1][ks], b1, acc[1][1], 0, 0, 0);
            }
        }

        // ---- cross-k-half reduction in LDS ----
        if (kh == 1) {
            float* rb = &red[w][lane][0];
            *(f32x4*)(rb + 0)  = acc[0][0];
            *(f32x4*)(rb + 4)  = acc[0][1];
            *(f32x4*)(rb + 8)  = acc[1][0];
            *(f32x4*)(rb + 12) = acc[1][1];
        }
        __syncthreads();
        if (kh == 0) {
            const float* rb = &red[w][lane][0];
            acc[0][0] += *(const f32x4*)(rb + 0);
            acc[0][1] += *(const f32x4*)(rb + 4);
            acc[1][0] += *(const f32x4*)(rb + 8);
            acc[1][1] += *(const f32x4*)(rb + 12);
            bf16* hout = hbuf + (size_t)((t + 1) & 1) * BATCH * HD;
            #pragma unroll
            for (int fn = 0; fn < 2; ++fn)
                #pragma unroll
                for (int fm = 0; fm < 2; ++fm) {
                    f32x4 pre = acc[fn][fm];
                    float gg = fast_tanh(pre[0]);
                    float ii = fast_sigmoid(pre[1]);
                    float ff = fast_sigmoid(pre[2]);
                    float oo = fast_sigmoid(pre[3]);
                    float s = gg * ii + st[fn][fm] * ff;
                    st[fn][fm] = s;
                    bf16 hv = (bf16)(fast_tanh(s) * oo);
                    unsigned hv32 = (unsigned)__builtin_bit_cast(unsigned short, hv);
                    const bf16* hp = hout + (size_t)(mr0 + fm * 16) * HD + hc0 + fn * 4;
                    asm volatile("global_store_short %0, %1, off sc0 sc1"
                                 :: "v"(hp), "v"(hv32) : "memory");
                }
        }
        __syncthreads();   // drains all waves' stores (vmcnt) before arrive
        if (tid == 0 && t < T_STEPS - 1)
            __hip_atomic_fetch_add(bar, 1, __ATOMIC_RELAXED, __HIP_MEMORY_SCOPE_AGENT);
    }
}

// ---------------- final projection: out[b][c] = h_T[b] @ Wph + bp ----------------
__global__ void proj_out(const bf16* __restrict__ h, const float* __restrict__ Wph,
                         const float* __restrict__ bp, float* __restrict__ out)
{
    __shared__ float red[256][10];
    int b = blockIdx.x, tid = threadIdx.x;
    float acc[10];
    #pragma unroll
    for (int c = 0; c < 10; ++c) acc[c] = 0.f;
    for (int k = tid; k < HD; k += 256) {
        float hv = (float)h[(size_t)b * HD + k];
        #pragma unroll
        for (int c = 0; c < 10; ++c)
            acc[c] += hv * Wph[k * 10 + c];
    }
    #pragma unroll
    for (int c = 0; c < 10; ++c) red[tid][c] = acc[c];
    __syncthreads();
    for (int s = 128; s > 0; s >>= 1) {
        if (tid < s) {
            #pragma unroll
            for (int c = 0; c < 10; ++c) red[tid][c] += red[tid + s][c];
        }
        __syncthreads();
    }
    if (tid < 10) out[b * 10 + tid] = red[0][tid] + bp[tid];
}

extern "C" void kernel_launch(void* const* d_in, const int* in_sizes, int n_in,
                              void* d_out, int out_size, void* d_ws, size_t ws_size,
                              hipStream_t stream)
{
    const int*   x   = (const int*)  d_in[0];
    const float* emb = (const float*)d_in[1];
    const float* Wgx = (const float*)d_in[2];
    const float* Wgh = (const float*)d_in[3];
    const float* Wix = (const float*)d_in[4];
    const float* Wih = (const float*)d_in[5];
    const float* Wfx = (const float*)d_in[6];
    const float* Wfh = (const float*)d_in[7];
    const float* Wox = (const float*)d_in[8];
    const float* Woh = (const float*)d_in[9];
    const float* bg  = (const float*)d_in[10];
    const float* bi  = (const float*)d_in[11];
    const float* bfv = (const float*)d_in[12];
    const float* bo  = (const float*)d_in[13];
    const float* Wph = (const float*)d_in[14];
    const float* bp  = (const float*)d_in[15];

    char* ws = (char*)d_ws;
    bf16*  WhpT = (bf16*)ws;                                   // 8 MB
    float* P    = (float*)(ws + 8388608);                      // 160 KB
    bf16*  hbuf = (bf16*)(ws + 8388608 + 163840);              // 2 x 512 KB
    int*   ctl  = (int*)(ws + 8388608 + 163840 + 1048576);     // 8 groups x 64B

    hipMemsetAsync(ctl, 0, 8 * 16 * sizeof(int), stream);
    build_P<<<160, 256, 0, stream>>>(emb, Wgx, Wix, Wfx, Wox, bg, bi, bfv, bo, P);
    build_W<<<1024, 256, 0, stream>>>(Wgh, Wih, Wfh, Woh, WhpT);

    void* args[] = { (void*)&x, (void*)&P, (void*)&WhpT, (void*)&hbuf, (void*)&ctl };
    hipLaunchCooperativeKernel((void*)lstm_main, dim3(256), dim3(512), args, 0, stream);

    proj_out<<<256, 256, 0, stream>>>(hbuf, Wph, bp, (float*)d_out);
}